// Round 4
// baseline (193.982 us; speedup 1.0000x reference)
//
#include <hip/hip_runtime.h>

#define N_   8
#define C_   128
#define H_   96
#define W_   96
#define G_   8
#define GC_  16
#define HW_  (H_ * W_)       // 9216
#define CHW_ (C_ * HW_)      // 1179648
#define OM_  216
#define OMP_ 224             // padded: 8 groups x 28 rows (27 live + 1 pad)
#define OMROWS2_ 112         // packed dword rows per sample (224/2)
#define EPS_ 1e-5f
#define BLKS_PER_N_ 192      // k_front blocks per sample (24 h-tiles * 8 groups)

typedef short bf16x8 __attribute__((ext_vector_type(8)));
typedef float f32x4 __attribute__((ext_vector_type(4)));

#if __has_builtin(__builtin_amdgcn_fdot2_f32_bf16)
#define HAVE_DOT2_ 1
typedef __bf16 bf16x2 __attribute__((ext_vector_type(2)));
static __device__ __forceinline__ bf16x2 u2bf2(unsigned int u) {
  union { unsigned int i; bf16x2 v; } c;
  c.i = u;
  return c.v;
}
#else
#define HAVE_DOT2_ 0
#endif

static __device__ __forceinline__ unsigned short f2bf(float f) {
  unsigned int u = __float_as_uint(f);
  unsigned int r = (u + 0x7fffu + ((u >> 16) & 1u)) >> 16;
  return (unsigned short)r;
}
static __device__ __forceinline__ float lo_bf(unsigned int u) {
  return __uint_as_float(u << 16);
}
static __device__ __forceinline__ float hi_bf(unsigned int u) {
  return __uint_as_float(u & 0xffff0000u);
}

// Branch-free exact-GELU via Abramowitz-Stegun 7.1.26 erf (|err| <= 1.5e-7,
// far below the bf16 quantization already applied to x1).
static __device__ __forceinline__ float fast_gelu(float z) {
  float s = z * 0.70710678118654752f;
  float as = fabsf(s);
  float t = __builtin_amdgcn_rcpf(fmaf(0.3275911f, as, 1.0f));
  float e = __expf(-as * as);
  float inner = fmaf(fmaf(fmaf(fmaf(1.061405429f, t, -1.453152027f), t,
                               1.421413741f), t, -0.284496736f), t, 0.254829592f);
  float y = fmaf(-inner * t, e, 1.0f);          // erf(|s|)
  float erf_s = copysignf(y, s);
  float hz = 0.5f * z;
  return fmaf(hz, erf_s, hz);
}

// Load one input row (5 cols: w0-1 .. w0+3) for a channel pair, zero-masked.
static __device__ __forceinline__ void loadrow5(float dst[2][5],
                                                const float* __restrict__ xp0,
                                                const float* __restrict__ xp1,
                                                int hh, int w0) {
  bool vy = (hh >= 0) & (hh < H_);
#pragma unroll
  for (int j = 0; j < 5; ++j) {
    int ww = w0 - 1 + j;
    bool v = vy & (ww >= 0) & (ww < W_);
    dst[0][j] = v ? xp0[hh * W_ + ww] : 0.0f;
    dst[1][j] = v ? xp1[hh * W_ + ww] : 0.0f;
  }
}

// ---------------------------------------------------------------------------
// K1 (fused): tile = 4 h x 96 w x 16 ch, grid (24, 8, 8) = 1536 blocks; LDS
// 27.6 KB -> 5 blocks/CU = 20 waves/CU. Thread = channel-pair x 3 px-cols,
// rolling 3x5 register window; pad-9 dword LDS transpose to px-major;
// packed bf16x2 stores. FETCH ~1.5x ideal (halo).
// ---------------------------------------------------------------------------
__global__ __launch_bounds__(256) void k_front(const float* __restrict__ x,
                                               const float* __restrict__ dw_w,
                                               const float* __restrict__ dw_b,
                                               unsigned short* __restrict__ xgb,
                                               unsigned short* __restrict__ x1b,
                                               float2* __restrict__ partials) {
  __shared__ unsigned int lds_c[384 * 9];   // raw centers, packed bf16x2, pad 9
  __shared__ unsigned int lds_a[384 * 9];   // conv outputs, packed bf16x2
  __shared__ float ls[4], lq[4];

  int tx = threadIdx.x;          // 0..31 (px-column triple)
  int ty = threadIdx.y;          // 0..7  (channel pair)
  int tid = ty * 32 + tx;
  int hb = blockIdx.x;           // 0..23
  int g  = blockIdx.y;           // 0..7
  int n  = blockIdx.z;
  int h0 = hb * 4;
  int w0 = tx * 3;

  const int c0 = g * 16 + 2 * ty;
  float wk[2][9];
  const float* wp = dw_w + c0 * 9;
#pragma unroll
  for (int j = 0; j < 9; ++j) {
    wk[0][j] = wp[j];
    wk[1][j] = wp[9 + j];
  }
  float bias[2] = {dw_b[c0], dw_b[c0 + 1]};

  const float* xp0 = x + ((size_t)(n * C_ + c0)) * HW_;
  const float* xp1 = xp0 + HW_;

  float s = 0.0f, q = 0.0f;

  float rr[3][2][5];
  loadrow5(rr[0], xp0, xp1, h0 - 1, w0);
  loadrow5(rr[1], xp0, xp1, h0,     w0);

#pragma unroll
  for (int r = 0; r < 4; ++r) {
    const int sA = r % 3;                // row h0+r-1
    const int sB = (r + 1) % 3;          // row h0+r
    const int sC = (r + 2) % 3;          // row h0+r+1
    loadrow5(rr[sC], xp0, xp1, h0 + r + 1, w0);

#pragma unroll
    for (int j = 0; j < 3; ++j) {
      float acc0 = bias[0], acc1 = bias[1];
#pragma unroll
      for (int dx = 0; dx < 3; ++dx) {
        acc0 = fmaf(rr[sA][0][j + dx], wk[0][0 + dx], acc0);
        acc1 = fmaf(rr[sA][1][j + dx], wk[1][0 + dx], acc1);
        acc0 = fmaf(rr[sB][0][j + dx], wk[0][3 + dx], acc0);
        acc1 = fmaf(rr[sB][1][j + dx], wk[1][3 + dx], acc1);
        acc0 = fmaf(rr[sC][0][j + dx], wk[0][6 + dx], acc0);
        acc1 = fmaf(rr[sC][1][j + dx], wk[1][6 + dx], acc1);
      }
      float cen0 = rr[sB][0][j + 1];
      float cen1 = rr[sB][1][j + 1];
      s += acc0 + acc1;
      q = fmaf(acc0, acc0, q);
      q = fmaf(acc1, acc1, q);
      int pxl = r * 96 + w0 + j;          // 0..383
      lds_a[pxl * 9 + ty] = (unsigned int)f2bf(acc0) |
                            ((unsigned int)f2bf(acc1) << 16);
      lds_c[pxl * 9 + ty] = (unsigned int)f2bf(cen0) |
                            ((unsigned int)f2bf(cen1) << 16);
    }
  }
  __syncthreads();

  // write-out: px-major, 32B per px per tile, fully coalesced
  for (int i = tid; i < 384; i += 256) {
    int p = h0 * W_ + i;                  // rows are contiguous in p
    unsigned int wc[8], wa[8];
#pragma unroll
    for (int k = 0; k < 8; ++k) {
      wc[k] = lds_c[i * 9 + k];
      wa[k] = lds_a[i * 9 + k];
    }
    unsigned int* xg = (unsigned int*)xgb + ((size_t)(n * G_ + g) * HW_ + p) * 8;
    uint4 c01 = {wc[0], wc[1], wc[2], wc[3]};
    uint4 c23 = {wc[4], wc[5], wc[6], wc[7]};
    *(uint4*)xg = c01;
    *(uint4*)(xg + 4) = c23;
    unsigned int* xb = (unsigned int*)x1b + ((size_t)n * HW_ + p) * 64 + g * 8;
    uint4 a01 = {wa[0], wa[1], wa[2], wa[3]};
    uint4 a23 = {wa[4], wa[5], wa[6], wa[7]};
    *(uint4*)xb = a01;
    *(uint4*)(xb + 4) = a23;
  }

  // block reduction of sum/sumsq
#pragma unroll
  for (int o = 32; o > 0; o >>= 1) {
    s += __shfl_down(s, o);
    q += __shfl_down(q, o);
  }
  int lane = tid & 63;
  int wv = tid >> 6;
  if (lane == 0) { ls[wv] = s; lq[wv] = q; }
  __syncthreads();
  if (tid == 0) {
    int bid = hb + 24 * g + BLKS_PER_N_ * n;
    partials[bid] = make_float2(ls[0] + ls[1] + ls[2] + ls[3],
                                lq[0] + lq[1] + lq[2] + lq[3]);
  }
}

// ---------------------------------------------------------------------------
// K1b+K1c merged (one launch): blocks 0..7 reduce partials -> stats[n];
// blocks 8..119 permute+pad om_w -> A bf16 [224x128] and biasp.
// ---------------------------------------------------------------------------
__global__ __launch_bounds__(256) void k_stats_prep(const float2* __restrict__ partials,
                                                    float* __restrict__ stats,
                                                    const float* __restrict__ om_w,
                                                    const float* __restrict__ om_b,
                                                    unsigned short* __restrict__ A,
                                                    float* __restrict__ biasp) {
  __shared__ float ls[4], lq[4];
  int b = blockIdx.x;
  int tid = threadIdx.x;
  if (b < N_) {
    int n = b;
    const float2* p = partials + n * BLKS_PER_N_;
    float s = 0.0f, q = 0.0f;
    if (tid < BLKS_PER_N_) {
      float2 v = p[tid];
      s = v.x;
      q = v.y;
    }
#pragma unroll
    for (int o = 32; o > 0; o >>= 1) {
      s += __shfl_down(s, o);
      q += __shfl_down(q, o);
    }
    int lane = tid & 63;
    int wv = tid >> 6;
    if (lane == 0) { ls[wv] = s; lq[wv] = q; }
    __syncthreads();
    if (tid == 0) {
      stats[n * 2 + 0] = ls[0] + ls[1] + ls[2] + ls[3];
      stats[n * 2 + 1] = lq[0] + lq[1] + lq[2] + lq[3];
    }
  } else {
    int idx = (b - N_) * 256 + tid;       // 0 .. 224*128-1
    int o = idx >> 7;
    int cix = idx & 127;
    int gg = o / 28;
    int k = o - gg * 28;
    float v = (k < 27) ? om_w[(gg * 27 + k) * C_ + cix] : 0.0f;
    A[idx] = f2bf(v);
    if (cix == 0) biasp[o] = (k < 27) ? om_b[gg * 27 + k] : 0.0f;
  }
}

// ---------------------------------------------------------------------------
// K4: MFMA GEMM with fused layernorm+GELU on the B operand.
// 32-px tiles -> grid (288, 8) = 2304 blocks; 4 waves/block split as
// 2 pixel-halves x 2 ot-halves (7 ot each). Output om2 bf16-packed.
// ---------------------------------------------------------------------------
__global__ __launch_bounds__(256) void k_gemm_mfma(const unsigned short* __restrict__ Bt,
                                                   const unsigned short* __restrict__ A,
                                                   const float* __restrict__ biasp,
                                                   const float* __restrict__ stats,
                                                   const float* __restrict__ gn_w,
                                                   const float* __restrict__ gn_b,
                                                   unsigned int* __restrict__ om2) {
  __shared__ unsigned short Bl[32 * 136];
  __shared__ alignas(16) float s_bias[OMP_];
  int tid = threadIdx.x;
  int pb = blockIdx.x;
  int n = blockIdx.y;
  int p0 = pb * 32;

  if (tid < OMP_ / 4) {
    ((float4*)s_bias)[tid] = ((const float4*)biasp)[tid];
  }

  float sum = stats[n * 2 + 0];
  float ssq = stats[n * 2 + 1];
  const float inv = 1.0f / (float)CHW_;
  float mean = sum * inv;
  float var = ssq * inv - mean * mean;
  float rstd = rsqrtf(var + EPS_);
  int cbase = (tid & 15) * 8;
  float a8[8], b8[8];
#pragma unroll
  for (int j = 0; j < 8; ++j) {
    float gw = gn_w[cbase + j];
    float gb = gn_b[cbase + j];
    a8[j] = rstd * gw;
    b8[j] = gb - mean * rstd * gw;
  }

  const unsigned short* src = Bt + ((size_t)n * HW_ + p0) * C_;
#pragma unroll
  for (int i = 0; i < 2; ++i) {
    int idx = i * 256 + tid;
    int row = idx >> 4;
    int col = idx & 15;                 // == tid & 15
    uint4 raw = *(const uint4*)(src + row * C_ + col * 8);
    unsigned int d[4] = {raw.x, raw.y, raw.z, raw.w};
    unsigned int od[4];
#pragma unroll
    for (int t = 0; t < 4; ++t) {
      float v0 = lo_bf(d[t]);
      float v1 = hi_bf(d[t]);
      float z0 = fmaf(v0, a8[2 * t], b8[2 * t]);
      float z1 = fmaf(v1, a8[2 * t + 1], b8[2 * t + 1]);
      float g0 = fast_gelu(z0);
      float g1 = fast_gelu(z1);
      od[t] = (unsigned int)f2bf(g0) | ((unsigned int)f2bf(g1) << 16);
    }
    uint4 packed = {od[0], od[1], od[2], od[3]};
    *(uint4*)(&Bl[row * 136 + col * 8]) = packed;
  }
  __syncthreads();

  int wave = tid >> 6;
  int lane = tid & 63;
  int quad = lane >> 4;
  int l16 = lane & 15;
  int pixhalf = wave & 1;               // which 16-px half of the tile
  int othalf = wave >> 1;               // which half of the 14 o-tiles
  int prow = pixhalf * 16 + l16;

  bf16x8 bfrag[4];
#pragma unroll
  for (int kk = 0; kk < 4; ++kk)
    bfrag[kk] = *(const bf16x8*)(&Bl[prow * 136 + kk * 32 + quad * 8]);

  int p = p0 + prow;
  for (int oi = 0; oi < 7; ++oi) {
    int ot = othalf * 7 + oi;
    const unsigned short* Ap = A + (ot * 16 + l16) * C_ + quad * 8;
    bf16x8 afrag[4];
#pragma unroll
    for (int kk = 0; kk < 4; ++kk)
      afrag[kk] = *(const bf16x8*)(Ap + kk * 32);

    f32x4 acc = {0.f, 0.f, 0.f, 0.f};
#pragma unroll
    for (int kk = 0; kk < 4; ++kk)
      acc = __builtin_amdgcn_mfma_f32_16x16x32_bf16(afrag[kk], bfrag[kk], acc, 0, 0, 0);

    int o0 = ot * 16 + quad * 4;               // even
    float4 bv = *(const float4*)(&s_bias[o0]);
    unsigned int pk0 = (unsigned int)f2bf(acc[0] + bv.x) |
                       ((unsigned int)f2bf(acc[1] + bv.y) << 16);
    unsigned int pk1 = (unsigned int)f2bf(acc[2] + bv.z) |
                       ((unsigned int)f2bf(acc[3] + bv.w) << 16);
    unsigned int* Cp = om2 + ((size_t)n * OMROWS2_ + (o0 >> 1)) * HW_ + p;
    Cp[0] = pk0;
    Cp[HW_] = pk1;
  }
}

// ---------------------------------------------------------------------------
// K5 (R12): deformable bilinear sampling, LDS-staged. Phase-2 xgb reads were
// 679 MB of L2 traffic (36x re-read of scattered 64B segments, ~20 us at the
// 34.5 TB/s L2 ceiling). Now each block stages rows [hs-2, he+2] of its
// (n,g) plane into LDS (<= 7 rows x 96 x 32 B = 21.5 KB, coalesced; total
// L2 traffic -75%) and phase 2 reads ds_read_b128 from LDS. Offsets with
// any corner row outside the window (|offy| >= 1, prob ~0 but not 0) fall
// back to global via sign-bit-tagged offsets -- correctness unconditional.
// LDS 30 KB -> 5 blocks/CU.
// ---------------------------------------------------------------------------
__global__ __launch_bounds__(256) void k_sample(const unsigned short* __restrict__ xgb,
                                                const unsigned int* __restrict__ om2,
                                                float* __restrict__ out) {
  __shared__ int4 s_wa[9 * 64];                 // {pk0, pk1, off_y0, off_y1}
  __shared__ unsigned short s_x[7 * W_ * GC_];  // staged rows, 21.5 KB

  int tid = threadIdx.x;
  int ord = blockIdx.x;
  int n = ord & 7;
  int t2 = ord >> 3;
  int g = t2 & 7;
  int pb = t2 >> 3;
  int p0 = pb * 64;

  int hs = p0 / W_;              // first strip row
  int he = (p0 + 63) / W_;       // last strip row (hs or hs+1)
  int w0r = max(hs - 2, 0);
  int w1r = min(he + 2, H_ - 1);

  const unsigned short* xbb = xgb + ((size_t)(n * G_ + g) * HW_) * GC_;

  // stage rows [w0r, w1r] into LDS, fully coalesced uint4 copies
  {
    const uint4* srcv = (const uint4*)(xbb + (size_t)w0r * W_ * GC_);
    uint4* dstv = (uint4*)s_x;
    int total = (w1r - w0r + 1) * (W_ * GC_ / 8);   // <= 1344
    for (int i = tid; i < total; i += 256) dstv[i] = srcv[i];
  }

  const unsigned int* omb = om2 + ((size_t)n * OMROWS2_ + g * 14) * HW_ + p0;
  for (int j = tid; j < 576; j += 256) {
    int pt = j >> 6;
    int px = j & 63;
    int p = p0 + px;
    int h = p / W_;
    int w = p - h * W_;
    unsigned int od = omb[pt * HW_ + px];
    float offx = lo_bf(od);
    float offy = hi_bf(od);
    unsigned int md = omb[(9 + (pt >> 1)) * HW_ + px];
    float m = (pt & 1) ? hi_bf(md) : lo_bf(md);
    float locy = (float)(h + pt / 3 - 1) + offy;
    float locx = (float)(w + pt % 3 - 1) + offx;
    float y0f = floorf(locy);
    float x0f = floorf(locx);
    float ly = locy - y0f;
    float lx = locx - x0f;
    int y0 = (int)y0f;
    int x0 = (int)x0f;
    int y1 = y0 + 1;
    int x1 = x0 + 1;
    bool vy0 = (y0 >= 0) & (y0 < H_);
    bool vy1 = (y1 >= 0) & (y1 < H_);
    bool vx0 = (x0 >= 0) & (x0 < W_);
    bool vx1 = (x1 >= 0) & (x1 < W_);
    float t0 = (1.0f - ly) * m;
    float t1 = ly * m;
    float u0 = 1.0f - lx;
    float w00 = (vy0 & vx0) ? t0 * u0 : 0.0f;
    float w01 = (vy0 & vx1) ? t0 * lx : 0.0f;
    float w10 = (vy1 & vx0) ? t1 * u0 : 0.0f;
    float w11 = (vy1 & vx1) ? t1 * lx : 0.0f;
    int yc0 = min(max(y0, 0), H_ - 1);
    int yc1 = min(max(y1, 0), H_ - 1);
    int xs  = min(max(x0, 0), W_ - 2);
    int idx0 = min(max(x0, 0), W_ - 1) - xs;       // 0 or 1
    int idx1 = min(max(x1, 0), W_ - 1) - xs;       // 0 or 1
    float wr0y0 = (idx0 == 0 ? w00 : 0.0f) + (idx1 == 0 ? w01 : 0.0f);
    float wr1y0 = (idx0 == 1 ? w00 : 0.0f) + (idx1 == 1 ? w01 : 0.0f);
    float wr0y1 = (idx0 == 0 ? w10 : 0.0f) + (idx1 == 0 ? w11 : 0.0f);
    float wr1y1 = (idx0 == 1 ? w10 : 0.0f) + (idx1 == 1 ? w11 : 0.0f);
    // corner-row offsets: LDS-relative if row staged, else global | signbit
    int z0, z1;
    if ((yc0 >= w0r) & (yc0 <= w1r))
      z0 = ((yc0 - w0r) * W_ + xs) * GC_;
    else
      z0 = (int)((unsigned int)((yc0 * W_ + xs) * GC_) | 0x80000000u);
    if ((yc1 >= w0r) & (yc1 <= w1r))
      z1 = ((yc1 - w0r) * W_ + xs) * GC_;
    else
      z1 = (int)((unsigned int)((yc1 * W_ + xs) * GC_) | 0x80000000u);
    int4 wa;
    wa.x = (int)((unsigned int)f2bf(wr0y0) | ((unsigned int)f2bf(wr0y1) << 16));
    wa.y = (int)((unsigned int)f2bf(wr1y0) | ((unsigned int)f2bf(wr1y1) << 16));
    wa.z = z0;
    wa.w = z1;
    s_wa[j] = wa;
  }
  __syncthreads();

  int px_l = tid >> 2;             // 0..63
  int sub = tid & 3;               // x-row = sub>>1, channel-chunk = sub&1
  int rowhalf = sub >> 1;
  int chunk = sub & 1;
  int p = p0 + px_l;

  float acc[8] = {0, 0, 0, 0, 0, 0, 0, 0};
#pragma unroll
  for (int pt = 0; pt < 9; ++pt) {
    int4 wa = s_wa[pt * 64 + px_l];
    unsigned int aw = (unsigned int)(rowhalf ? wa.y : wa.x);  // (w_y0, w_y1) bf16x2
    uint4 r0, r1;
    if (wa.z >= 0) r0 = *(const uint4*)(s_x + wa.z + sub * 8);
    else           r0 = *(const uint4*)(xbb + (wa.z & 0x7fffffff) + sub * 8);
    if (wa.w >= 0) r1 = *(const uint4*)(s_x + wa.w + sub * 8);
    else           r1 = *(const uint4*)(xbb + (wa.w & 0x7fffffff) + sub * 8);
    unsigned int d0[4] = {r0.x, r0.y, r0.z, r0.w};
    unsigned int d1[4] = {r1.x, r1.y, r1.z, r1.w};
#if HAVE_DOT2_
    bf16x2 a2 = u2bf2(aw);
#pragma unroll
    for (int t = 0; t < 4; ++t) {
      unsigned int blo = __builtin_amdgcn_perm(d1[t], d0[t], 0x05040100u); // (v0.lo, v1.lo)
      unsigned int bhi = __builtin_amdgcn_perm(d1[t], d0[t], 0x07060302u); // (v0.hi, v1.hi)
      acc[2 * t]     = __builtin_amdgcn_fdot2_f32_bf16(a2, u2bf2(blo), acc[2 * t], false);
      acc[2 * t + 1] = __builtin_amdgcn_fdot2_f32_bf16(a2, u2bf2(bhi), acc[2 * t + 1], false);
    }
#else
    float w0 = lo_bf(aw);
    float w1 = hi_bf(aw);
#pragma unroll
    for (int t = 0; t < 4; ++t) {
      acc[2 * t]     = fmaf(w0, lo_bf(d0[t]), acc[2 * t]);
      acc[2 * t + 1] = fmaf(w0, hi_bf(d0[t]), acc[2 * t + 1]);
      acc[2 * t]     = fmaf(w1, lo_bf(d1[t]), acc[2 * t]);
      acc[2 * t + 1] = fmaf(w1, hi_bf(d1[t]), acc[2 * t + 1]);
    }
#endif
  }

  // fold the two x-rows (lanes sub and sub^2 hold the same 8 channels)
#pragma unroll
  for (int i = 0; i < 8; ++i) acc[i] += __shfl_xor(acc[i], 2);

  int ch = chunk * 8 + rowhalf * 4;
  float* op = out + ((size_t)(n * C_ + g * GC_ + ch)) * HW_ + p;
#pragma unroll
  for (int r = 0; r < 4; ++r) op[r * HW_] = acc[rowhalf * 4 + r];
}

// ---------------------------------------------------------------------------
extern "C" void kernel_launch(void* const* d_in, const int* in_sizes, int n_in,
                              void* d_out, int out_size, void* d_ws, size_t ws_size,
                              hipStream_t stream) {
  const float* x    = (const float*)d_in[0];
  const float* dw_w = (const float*)d_in[1];
  const float* dw_b = (const float*)d_in[2];
  const float* gn_w = (const float*)d_in[3];
  const float* gn_b = (const float*)d_in[4];
  const float* om_w = (const float*)d_in[5];
  const float* om_b = (const float*)d_in[6];
  float* out = (float*)d_out;

  // workspace layout (~71 MB)
  unsigned short* xgb = (unsigned short*)d_ws;                       // 9437184 us
  unsigned short* x1b = xgb + (size_t)N_ * CHW_;                     // 9437184 us
  unsigned int* om2 = (unsigned int*)(x1b + (size_t)N_ * CHW_);      // 8*112*9216 u32
  float* stats = (float*)(om2 + (size_t)N_ * OMROWS2_ * HW_);        // 16 f
  float2* partials = (float2*)(stats + 16);                          // 1536 float2
  unsigned short* Abf = (unsigned short*)(partials + N_ * BLKS_PER_N_);
  float* biasp = (float*)(Abf + OMP_ * C_);                          // 224 f

  k_front<<<dim3(24, G_, N_), dim3(32, 8), 0, stream>>>(
      x, dw_w, dw_b, xgb, x1b, partials);
  k_stats_prep<<<N_ + 112, 256, 0, stream>>>(partials, stats, om_w, om_b, Abf, biasp);
  k_gemm_mfma<<<dim3(HW_ / 32, N_), 256, 0, stream>>>(
      x1b, Abf, biasp, stats, gn_w, gn_b, om2);
  k_sample<<<9216, 256, 0, stream>>>(xgb, om2, out);
}

// Round 5
// 184.212 us; speedup vs baseline: 1.0530x; 1.0530x over previous
//
#include <hip/hip_runtime.h>

#define N_   8
#define C_   128
#define H_   96
#define W_   96
#define G_   8
#define GC_  16
#define HW_  (H_ * W_)       // 9216
#define CHW_ (C_ * HW_)      // 1179648
#define OM_  216
#define OMP_ 224             // padded: 8 groups x 28 rows (27 live + 1 pad)
#define OMROWS2_ 112         // packed dword rows per sample (224/2)
#define EPS_ 1e-5f
#define BLKS_PER_N_ 192      // k_front blocks per sample (24 h-tiles * 8 groups)

typedef short bf16x8 __attribute__((ext_vector_type(8)));
typedef float f32x4 __attribute__((ext_vector_type(4)));

#if __has_builtin(__builtin_amdgcn_fdot2_f32_bf16)
#define HAVE_DOT2_ 1
typedef __bf16 bf16x2 __attribute__((ext_vector_type(2)));
static __device__ __forceinline__ bf16x2 u2bf2(unsigned int u) {
  union { unsigned int i; bf16x2 v; } c;
  c.i = u;
  return c.v;
}
#else
#define HAVE_DOT2_ 0
#endif

static __device__ __forceinline__ unsigned short f2bf(float f) {
  unsigned int u = __float_as_uint(f);
  unsigned int r = (u + 0x7fffu + ((u >> 16) & 1u)) >> 16;
  return (unsigned short)r;
}
static __device__ __forceinline__ float lo_bf(unsigned int u) {
  return __uint_as_float(u << 16);
}
static __device__ __forceinline__ float hi_bf(unsigned int u) {
  return __uint_as_float(u & 0xffff0000u);
}

// Branch-free exact-GELU via Abramowitz-Stegun 7.1.26 erf (|err| <= 1.5e-7,
// far below the bf16 quantization already applied to x1).
static __device__ __forceinline__ float fast_gelu(float z) {
  float s = z * 0.70710678118654752f;
  float as = fabsf(s);
  float t = __builtin_amdgcn_rcpf(fmaf(0.3275911f, as, 1.0f));
  float e = __expf(-as * as);
  float inner = fmaf(fmaf(fmaf(fmaf(1.061405429f, t, -1.453152027f), t,
                               1.421413741f), t, -0.284496736f), t, 0.254829592f);
  float y = fmaf(-inner * t, e, 1.0f);          // erf(|s|)
  float erf_s = copysignf(y, s);
  float hz = 0.5f * z;
  return fmaf(hz, erf_s, hz);
}

// Load one input row (5 cols: w0-1 .. w0+3) for a channel pair, zero-masked.
static __device__ __forceinline__ void loadrow5(float dst[2][5],
                                                const float* __restrict__ xp0,
                                                const float* __restrict__ xp1,
                                                int hh, int w0) {
  bool vy = (hh >= 0) & (hh < H_);
#pragma unroll
  for (int j = 0; j < 5; ++j) {
    int ww = w0 - 1 + j;
    bool v = vy & (ww >= 0) & (ww < W_);
    dst[0][j] = v ? xp0[hh * W_ + ww] : 0.0f;
    dst[1][j] = v ? xp1[hh * W_ + ww] : 0.0f;
  }
}

// ---------------------------------------------------------------------------
// K1 (fused): tile = 4 h x 96 w x 16 ch, grid (24, 8, 8) = 1536 blocks; LDS
// 27.6 KB -> 5 blocks/CU = 20 waves/CU. Thread = channel-pair x 3 px-cols,
// rolling 3x5 register window; pad-9 dword LDS transpose to px-major;
// packed bf16x2 stores. FETCH ~1.5x ideal (halo).
// ---------------------------------------------------------------------------
__global__ __launch_bounds__(256) void k_front(const float* __restrict__ x,
                                               const float* __restrict__ dw_w,
                                               const float* __restrict__ dw_b,
                                               unsigned short* __restrict__ xgb,
                                               unsigned short* __restrict__ x1b,
                                               float2* __restrict__ partials) {
  __shared__ unsigned int lds_c[384 * 9];   // raw centers, packed bf16x2, pad 9
  __shared__ unsigned int lds_a[384 * 9];   // conv outputs, packed bf16x2
  __shared__ float ls[4], lq[4];

  int tx = threadIdx.x;          // 0..31 (px-column triple)
  int ty = threadIdx.y;          // 0..7  (channel pair)
  int tid = ty * 32 + tx;
  int hb = blockIdx.x;           // 0..23
  int g  = blockIdx.y;           // 0..7
  int n  = blockIdx.z;
  int h0 = hb * 4;
  int w0 = tx * 3;

  const int c0 = g * 16 + 2 * ty;
  float wk[2][9];
  const float* wp = dw_w + c0 * 9;
#pragma unroll
  for (int j = 0; j < 9; ++j) {
    wk[0][j] = wp[j];
    wk[1][j] = wp[9 + j];
  }
  float bias[2] = {dw_b[c0], dw_b[c0 + 1]};

  const float* xp0 = x + ((size_t)(n * C_ + c0)) * HW_;
  const float* xp1 = xp0 + HW_;

  float s = 0.0f, q = 0.0f;

  float rr[3][2][5];
  loadrow5(rr[0], xp0, xp1, h0 - 1, w0);
  loadrow5(rr[1], xp0, xp1, h0,     w0);

#pragma unroll
  for (int r = 0; r < 4; ++r) {
    const int sA = r % 3;                // row h0+r-1
    const int sB = (r + 1) % 3;          // row h0+r
    const int sC = (r + 2) % 3;          // row h0+r+1
    loadrow5(rr[sC], xp0, xp1, h0 + r + 1, w0);

#pragma unroll
    for (int j = 0; j < 3; ++j) {
      float acc0 = bias[0], acc1 = bias[1];
#pragma unroll
      for (int dx = 0; dx < 3; ++dx) {
        acc0 = fmaf(rr[sA][0][j + dx], wk[0][0 + dx], acc0);
        acc1 = fmaf(rr[sA][1][j + dx], wk[1][0 + dx], acc1);
        acc0 = fmaf(rr[sB][0][j + dx], wk[0][3 + dx], acc0);
        acc1 = fmaf(rr[sB][1][j + dx], wk[1][3 + dx], acc1);
        acc0 = fmaf(rr[sC][0][j + dx], wk[0][6 + dx], acc0);
        acc1 = fmaf(rr[sC][1][j + dx], wk[1][6 + dx], acc1);
      }
      float cen0 = rr[sB][0][j + 1];
      float cen1 = rr[sB][1][j + 1];
      s += acc0 + acc1;
      q = fmaf(acc0, acc0, q);
      q = fmaf(acc1, acc1, q);
      int pxl = r * 96 + w0 + j;          // 0..383
      lds_a[pxl * 9 + ty] = (unsigned int)f2bf(acc0) |
                            ((unsigned int)f2bf(acc1) << 16);
      lds_c[pxl * 9 + ty] = (unsigned int)f2bf(cen0) |
                            ((unsigned int)f2bf(cen1) << 16);
    }
  }
  __syncthreads();

  // write-out: px-major, 32B per px per tile, fully coalesced
  for (int i = tid; i < 384; i += 256) {
    int p = h0 * W_ + i;                  // rows are contiguous in p
    unsigned int wc[8], wa[8];
#pragma unroll
    for (int k = 0; k < 8; ++k) {
      wc[k] = lds_c[i * 9 + k];
      wa[k] = lds_a[i * 9 + k];
    }
    unsigned int* xg = (unsigned int*)xgb + ((size_t)(n * G_ + g) * HW_ + p) * 8;
    uint4 c01 = {wc[0], wc[1], wc[2], wc[3]};
    uint4 c23 = {wc[4], wc[5], wc[6], wc[7]};
    *(uint4*)xg = c01;
    *(uint4*)(xg + 4) = c23;
    unsigned int* xb = (unsigned int*)x1b + ((size_t)n * HW_ + p) * 64 + g * 8;
    uint4 a01 = {wa[0], wa[1], wa[2], wa[3]};
    uint4 a23 = {wa[4], wa[5], wa[6], wa[7]};
    *(uint4*)xb = a01;
    *(uint4*)(xb + 4) = a23;
  }

  // block reduction of sum/sumsq
#pragma unroll
  for (int o = 32; o > 0; o >>= 1) {
    s += __shfl_down(s, o);
    q += __shfl_down(q, o);
  }
  int lane = tid & 63;
  int wv = tid >> 6;
  if (lane == 0) { ls[wv] = s; lq[wv] = q; }
  __syncthreads();
  if (tid == 0) {
    int bid = hb + 24 * g + BLKS_PER_N_ * n;
    partials[bid] = make_float2(ls[0] + ls[1] + ls[2] + ls[3],
                                lq[0] + lq[1] + lq[2] + lq[3]);
  }
}

// ---------------------------------------------------------------------------
// K1c: permute+pad om_w -> A bf16 [224x128] + biasp. No dependency on
// k_front, so it launches FIRST (the stats half that previously sat between
// front and gemm is now fused into k_gemm_mfma).
// ---------------------------------------------------------------------------
__global__ __launch_bounds__(256) void k_prep(const float* __restrict__ om_w,
                                              const float* __restrict__ om_b,
                                              unsigned short* __restrict__ A,
                                              float* __restrict__ biasp) {
  int idx = blockIdx.x * 256 + threadIdx.x;   // 0 .. 224*128-1
  int o = idx >> 7;
  int cix = idx & 127;
  int g = o / 28;
  int k = o - g * 28;
  float v = (k < 27) ? om_w[(g * 27 + k) * C_ + cix] : 0.0f;
  A[idx] = f2bf(v);
  if (cix == 0) biasp[o] = (k < 27) ? om_b[g * 27 + k] : 0.0f;
}

// ---------------------------------------------------------------------------
// K4: MFMA GEMM with fused layernorm+GELU on the B operand, R13: also fuses
// the per-sample stats reduction (192 float2 partials, per-wave shfl tree --
// bit-identical order to the old k_stats) so the stats kernel leaves the
// critical path. 32-px tiles -> grid (288, 8) = 2304 blocks; 4 waves split
// as 2 pixel-halves x 2 ot-halves. Output om2 bf16-packed.
// ---------------------------------------------------------------------------
__global__ __launch_bounds__(256) void k_gemm_mfma(const unsigned short* __restrict__ Bt,
                                                   const unsigned short* __restrict__ A,
                                                   const float* __restrict__ biasp,
                                                   const float2* __restrict__ partials,
                                                   const float* __restrict__ gn_w,
                                                   const float* __restrict__ gn_b,
                                                   unsigned int* __restrict__ om2) {
  __shared__ unsigned short Bl[32 * 136];
  __shared__ alignas(16) float s_bias[OMP_];
  __shared__ float ls[4], lq[4];
  int tid = threadIdx.x;
  int pb = blockIdx.x;
  int n = blockIdx.y;
  int p0 = pb * 32;

  // inline stats reduction (was k_stats): 192 partials for this n
  {
    float s = 0.0f, q = 0.0f;
    if (tid < BLKS_PER_N_) {
      float2 v = partials[n * BLKS_PER_N_ + tid];
      s = v.x;
      q = v.y;
    }
#pragma unroll
    for (int o = 32; o > 0; o >>= 1) {
      s += __shfl_down(s, o);
      q += __shfl_down(q, o);
    }
    int lane = tid & 63;
    int wv = tid >> 6;
    if (lane == 0) { ls[wv] = s; lq[wv] = q; }
  }
  if (tid < OMP_ / 4) {
    ((float4*)s_bias)[tid] = ((const float4*)biasp)[tid];
  }
  __syncthreads();

  float sum = ls[0] + ls[1] + ls[2] + ls[3];
  float ssq = lq[0] + lq[1] + lq[2] + lq[3];
  const float inv = 1.0f / (float)CHW_;
  float mean = sum * inv;
  float var = ssq * inv - mean * mean;
  float rstd = rsqrtf(var + EPS_);
  int cbase = (tid & 15) * 8;
  float a8[8], b8[8];
#pragma unroll
  for (int j = 0; j < 8; ++j) {
    float gw = gn_w[cbase + j];
    float gb = gn_b[cbase + j];
    a8[j] = rstd * gw;
    b8[j] = gb - mean * rstd * gw;
  }

  const unsigned short* src = Bt + ((size_t)n * HW_ + p0) * C_;
#pragma unroll
  for (int i = 0; i < 2; ++i) {
    int idx = i * 256 + tid;
    int row = idx >> 4;
    int col = idx & 15;                 // == tid & 15
    uint4 raw = *(const uint4*)(src + row * C_ + col * 8);
    unsigned int d[4] = {raw.x, raw.y, raw.z, raw.w};
    unsigned int od[4];
#pragma unroll
    for (int t = 0; t < 4; ++t) {
      float v0 = lo_bf(d[t]);
      float v1 = hi_bf(d[t]);
      float z0 = fmaf(v0, a8[2 * t], b8[2 * t]);
      float z1 = fmaf(v1, a8[2 * t + 1], b8[2 * t + 1]);
      float g0 = fast_gelu(z0);
      float g1 = fast_gelu(z1);
      od[t] = (unsigned int)f2bf(g0) | ((unsigned int)f2bf(g1) << 16);
    }
    uint4 packed = {od[0], od[1], od[2], od[3]};
    *(uint4*)(&Bl[row * 136 + col * 8]) = packed;
  }
  __syncthreads();

  int wave = tid >> 6;
  int lane = tid & 63;
  int quad = lane >> 4;
  int l16 = lane & 15;
  int pixhalf = wave & 1;               // which 16-px half of the tile
  int othalf = wave >> 1;               // which half of the 14 o-tiles
  int prow = pixhalf * 16 + l16;

  bf16x8 bfrag[4];
#pragma unroll
  for (int kk = 0; kk < 4; ++kk)
    bfrag[kk] = *(const bf16x8*)(&Bl[prow * 136 + kk * 32 + quad * 8]);

  int p = p0 + prow;
  for (int oi = 0; oi < 7; ++oi) {
    int ot = othalf * 7 + oi;
    const unsigned short* Ap = A + (ot * 16 + l16) * C_ + quad * 8;
    bf16x8 afrag[4];
#pragma unroll
    for (int kk = 0; kk < 4; ++kk)
      afrag[kk] = *(const bf16x8*)(Ap + kk * 32);

    f32x4 acc = {0.f, 0.f, 0.f, 0.f};
#pragma unroll
    for (int kk = 0; kk < 4; ++kk)
      acc = __builtin_amdgcn_mfma_f32_16x16x32_bf16(afrag[kk], bfrag[kk], acc, 0, 0, 0);

    int o0 = ot * 16 + quad * 4;               // even
    float4 bv = *(const float4*)(&s_bias[o0]);
    unsigned int pk0 = (unsigned int)f2bf(acc[0] + bv.x) |
                       ((unsigned int)f2bf(acc[1] + bv.y) << 16);
    unsigned int pk1 = (unsigned int)f2bf(acc[2] + bv.z) |
                       ((unsigned int)f2bf(acc[3] + bv.w) << 16);
    unsigned int* Cp = om2 + ((size_t)n * OMROWS2_ + (o0 >> 1)) * HW_ + p;
    Cp[0] = pk0;
    Cp[HW_] = pk1;
  }
}

// ---------------------------------------------------------------------------
// K5: deformable bilinear sampling from bf16 group-planar xgb (R11 form:
// global reads -- per-block working set is 21.5 KB and L1-resident; R12's
// LDS staging regressed via occupancy loss + bank conflicts + dual-path
// VALU). Phase 1 (576 jobs): redistribute corner weights onto physical rows
// xs/xs+1, pack (y0,y1) weights per x-row as bf16 pair, emit int4 per
// (pt,px). Phase 2: 4 lanes/px; per pt: 1 ds_read_b128 + 2 global dwordx4 +
// 8 v_perm + 8 v_dot2; __shfl_xor(2) folds x-rows. Grid: 9216 blocks.
// ---------------------------------------------------------------------------
__global__ __launch_bounds__(256) void k_sample(const unsigned short* __restrict__ xgb,
                                                const unsigned int* __restrict__ om2,
                                                float* __restrict__ out) {
  __shared__ int4 s_wa[9 * 64];   // {pk0, pk1, off_y0, off_y1}

  int tid = threadIdx.x;
  int ord = blockIdx.x;
  int n = ord & 7;
  int t2 = ord >> 3;
  int g = t2 & 7;
  int pb = t2 >> 3;
  int p0 = pb * 64;

  const unsigned int* omb = om2 + ((size_t)n * OMROWS2_ + g * 14) * HW_ + p0;
  for (int j = tid; j < 576; j += 256) {
    int pt = j >> 6;
    int px = j & 63;
    int p = p0 + px;
    int h = p / W_;
    int w = p - h * W_;
    unsigned int od = omb[pt * HW_ + px];
    float offx = lo_bf(od);
    float offy = hi_bf(od);
    unsigned int md = omb[(9 + (pt >> 1)) * HW_ + px];
    float m = (pt & 1) ? hi_bf(md) : lo_bf(md);
    float locy = (float)(h + pt / 3 - 1) + offy;
    float locx = (float)(w + pt % 3 - 1) + offx;
    float y0f = floorf(locy);
    float x0f = floorf(locx);
    float ly = locy - y0f;
    float lx = locx - x0f;
    int y0 = (int)y0f;
    int x0 = (int)x0f;
    int y1 = y0 + 1;
    int x1 = x0 + 1;
    bool vy0 = (y0 >= 0) & (y0 < H_);
    bool vy1 = (y1 >= 0) & (y1 < H_);
    bool vx0 = (x0 >= 0) & (x0 < W_);
    bool vx1 = (x1 >= 0) & (x1 < W_);
    float t0 = (1.0f - ly) * m;
    float t1 = ly * m;
    float u0 = 1.0f - lx;
    float w00 = (vy0 & vx0) ? t0 * u0 : 0.0f;
    float w01 = (vy0 & vx1) ? t0 * lx : 0.0f;
    float w10 = (vy1 & vx0) ? t1 * u0 : 0.0f;
    float w11 = (vy1 & vx1) ? t1 * lx : 0.0f;
    int yc0 = min(max(y0, 0), H_ - 1);
    int yc1 = min(max(y1, 0), H_ - 1);
    int xs  = min(max(x0, 0), W_ - 2);
    int idx0 = min(max(x0, 0), W_ - 1) - xs;       // 0 or 1
    int idx1 = min(max(x1, 0), W_ - 1) - xs;       // 0 or 1
    float wr0y0 = (idx0 == 0 ? w00 : 0.0f) + (idx1 == 0 ? w01 : 0.0f);
    float wr1y0 = (idx0 == 1 ? w00 : 0.0f) + (idx1 == 1 ? w01 : 0.0f);
    float wr0y1 = (idx0 == 0 ? w10 : 0.0f) + (idx1 == 0 ? w11 : 0.0f);
    float wr1y1 = (idx0 == 1 ? w10 : 0.0f) + (idx1 == 1 ? w11 : 0.0f);
    int4 wa;
    wa.x = (int)((unsigned int)f2bf(wr0y0) | ((unsigned int)f2bf(wr0y1) << 16));
    wa.y = (int)((unsigned int)f2bf(wr1y0) | ((unsigned int)f2bf(wr1y1) << 16));
    wa.z = (yc0 * W_ + xs) * GC_;
    wa.w = (yc1 * W_ + xs) * GC_;
    s_wa[j] = wa;
  }
  __syncthreads();

  int px_l = tid >> 2;             // 0..63
  int sub = tid & 3;               // x-col = sub>>1? no: sub indexes (x-col, ch-chunk)
  int rowhalf = sub >> 1;
  int chunk = sub & 1;
  int p = p0 + px_l;
  const unsigned short* xbb = xgb + ((size_t)(n * G_ + g) * HW_) * GC_;

  float acc[8] = {0, 0, 0, 0, 0, 0, 0, 0};
#pragma unroll
  for (int pt = 0; pt < 9; ++pt) {
    int4 wa = s_wa[pt * 64 + px_l];
    unsigned int aw = (unsigned int)(rowhalf ? wa.y : wa.x);  // (w_y0, w_y1) bf16x2
    uint4 r0 = *(const uint4*)(xbb + wa.z + sub * 8);         // y0 row-pair
    uint4 r1 = *(const uint4*)(xbb + wa.w + sub * 8);         // y1 row-pair
    unsigned int d0[4] = {r0.x, r0.y, r0.z, r0.w};
    unsigned int d1[4] = {r1.x, r1.y, r1.z, r1.w};
#if HAVE_DOT2_
    bf16x2 a2 = u2bf2(aw);
#pragma unroll
    for (int t = 0; t < 4; ++t) {
      unsigned int blo = __builtin_amdgcn_perm(d1[t], d0[t], 0x05040100u); // (v0.lo, v1.lo)
      unsigned int bhi = __builtin_amdgcn_perm(d1[t], d0[t], 0x07060302u); // (v0.hi, v1.hi)
      acc[2 * t]     = __builtin_amdgcn_fdot2_f32_bf16(a2, u2bf2(blo), acc[2 * t], false);
      acc[2 * t + 1] = __builtin_amdgcn_fdot2_f32_bf16(a2, u2bf2(bhi), acc[2 * t + 1], false);
    }
#else
    float w0 = lo_bf(aw);
    float w1 = hi_bf(aw);
#pragma unroll
    for (int t = 0; t < 4; ++t) {
      acc[2 * t]     = fmaf(w0, lo_bf(d0[t]), acc[2 * t]);
      acc[2 * t + 1] = fmaf(w0, hi_bf(d0[t]), acc[2 * t + 1]);
      acc[2 * t]     = fmaf(w1, lo_bf(d1[t]), acc[2 * t]);
      acc[2 * t + 1] = fmaf(w1, hi_bf(d1[t]), acc[2 * t + 1]);
    }
#endif
  }

  // fold the two x-cols (lanes sub and sub^2 hold the same 8 channels)
#pragma unroll
  for (int i = 0; i < 8; ++i) acc[i] += __shfl_xor(acc[i], 2);

  int ch = chunk * 8 + rowhalf * 4;
  float* op = out + ((size_t)(n * C_ + g * GC_ + ch)) * HW_ + p;
#pragma unroll
  for (int r = 0; r < 4; ++r) op[r * HW_] = acc[rowhalf * 4 + r];
}

// ---------------------------------------------------------------------------
extern "C" void kernel_launch(void* const* d_in, const int* in_sizes, int n_in,
                              void* d_out, int out_size, void* d_ws, size_t ws_size,
                              hipStream_t stream) {
  const float* x    = (const float*)d_in[0];
  const float* dw_w = (const float*)d_in[1];
  const float* dw_b = (const float*)d_in[2];
  const float* gn_w = (const float*)d_in[3];
  const float* gn_b = (const float*)d_in[4];
  const float* om_w = (const float*)d_in[5];
  const float* om_b = (const float*)d_in[6];
  float* out = (float*)d_out;

  // workspace layout (~71 MB)
  unsigned short* xgb = (unsigned short*)d_ws;                       // 9437184 us
  unsigned short* x1b = xgb + (size_t)N_ * CHW_;                     // 9437184 us
  unsigned int* om2 = (unsigned int*)(x1b + (size_t)N_ * CHW_);      // 8*112*9216 u32
  float* stats = (float*)(om2 + (size_t)N_ * OMROWS2_ * HW_);        // 16 f (unused)
  float2* partials = (float2*)(stats + 16);                          // 1536 float2
  unsigned short* Abf = (unsigned short*)(partials + N_ * BLKS_PER_N_);
  float* biasp = (float*)(Abf + OMP_ * C_);                          // 224 f

  k_prep<<<(OMP_ * C_) / 256, 256, 0, stream>>>(om_w, om_b, Abf, biasp);
  k_front<<<dim3(24, G_, N_), dim3(32, 8), 0, stream>>>(
      x, dw_w, dw_b, xgb, x1b, partials);
  k_gemm_mfma<<<dim3(HW_ / 32, N_), 256, 0, stream>>>(
      x1b, Abf, biasp, partials, gn_w, gn_b, om2);
  k_sample<<<9216, 256, 0, stream>>>(xgb, om2, out);
}

// Round 6
// 181.716 us; speedup vs baseline: 1.0675x; 1.0137x over previous
//
#include <hip/hip_runtime.h>
#include <hip/hip_bf16.h>

#define N_   8
#define C_   128
#define H_   96
#define W_   96
#define G_   8
#define GC_  16
#define HW_  (H_ * W_)       // 9216
#define CHW_ (C_ * HW_)      // 1179648
#define OM_  216
#define OMP_ 224             // padded: 8 groups x 28 rows (27 live + 1 pad)
#define OMROWS2_ 112         // packed dword rows per sample (224/2)
#define EPS_ 1e-5f
#define BLKS_PER_N_ 192      // k_front blocks per sample (24 h-tiles * 8 groups)
#define PW_  100             // padded plane width (96 + 2*2)
#define PPLANE_ (PW_ * PW_ * GC_)   // shorts per padded (n,g) plane = 160000

typedef short bf16x8 __attribute__((ext_vector_type(8)));
typedef float f32x4 __attribute__((ext_vector_type(4)));

#if __has_builtin(__builtin_amdgcn_fdot2_f32_bf16)
#define HAVE_DOT2_ 1
typedef __bf16 bf16x2 __attribute__((ext_vector_type(2)));
static __device__ __forceinline__ bf16x2 u2bf2(unsigned int u) {
  union { unsigned int i; bf16x2 v; } c;
  c.i = u;
  return c.v;
}
#else
#define HAVE_DOT2_ 0
#endif

static __device__ __forceinline__ unsigned short f2bf(float f) {
  unsigned int u = __float_as_uint(f);
  unsigned int r = (u + 0x7fffu + ((u >> 16) & 1u)) >> 16;
  return (unsigned short)r;
}
// Packed f32x2 -> bf16x2 via v_cvt_pk_bf16_f32 (1 instr, RTNE -- bit-identical
// to f2bf's manual rounding). Replaces ~10 VALU ops per pack.
static __device__ __forceinline__ unsigned int pk_bf2(float lo, float hi) {
  __hip_bfloat162 h = __float22bfloat162_rn(make_float2(lo, hi));
  union { __hip_bfloat162 h; unsigned int u; } c;
  c.h = h;
  return c.u;
}
static __device__ __forceinline__ float lo_bf(unsigned int u) {
  return __uint_as_float(u << 16);
}
static __device__ __forceinline__ float hi_bf(unsigned int u) {
  return __uint_as_float(u & 0xffff0000u);
}

// Branch-free exact-GELU via Abramowitz-Stegun 7.1.26 erf (|err| <= 1.5e-7,
// far below the bf16 quantization already applied to x1).
static __device__ __forceinline__ float fast_gelu(float z) {
  float s = z * 0.70710678118654752f;
  float as = fabsf(s);
  float t = __builtin_amdgcn_rcpf(fmaf(0.3275911f, as, 1.0f));
  float e = __expf(-as * as);
  float inner = fmaf(fmaf(fmaf(fmaf(1.061405429f, t, -1.453152027f), t,
                               1.421413741f), t, -0.284496736f), t, 0.254829592f);
  float y = fmaf(-inner * t, e, 1.0f);          // erf(|s|)
  float erf_s = copysignf(y, s);
  float hz = 0.5f * z;
  return fmaf(hz, erf_s, hz);
}

// Load one input row (5 cols: w0-1 .. w0+3) for a channel pair, zero-masked.
static __device__ __forceinline__ void loadrow5(float dst[2][5],
                                                const float* __restrict__ xp0,
                                                const float* __restrict__ xp1,
                                                int hh, int w0) {
  bool vy = (hh >= 0) & (hh < H_);
#pragma unroll
  for (int j = 0; j < 5; ++j) {
    int ww = w0 - 1 + j;
    bool v = vy & (ww >= 0) & (ww < W_);
    dst[0][j] = v ? xp0[hh * W_ + ww] : 0.0f;
    dst[1][j] = v ? xp1[hh * W_ + ww] : 0.0f;
  }
}

// ---------------------------------------------------------------------------
// K1 (fused): tile = 4 h x 96 w x 16 ch, grid (24, 8, 8) = 1536 blocks; LDS
// 27.6 KB -> 5 blocks/CU. Thread = channel-pair x 3 px-cols, rolling 3x5
// register window; pad-9 dword LDS transpose; cvt_pk bf16 packing (R14:
// replaces ~240 manual-pack VALU ops/thread with 24 cvt_pk).
// xgb written as zero-padded 100x100 plane (border pre-zeroed by k_prep).
// ---------------------------------------------------------------------------
__global__ __launch_bounds__(256) void k_front(const float* __restrict__ x,
                                               const float* __restrict__ dw_w,
                                               const float* __restrict__ dw_b,
                                               unsigned short* __restrict__ xgb,
                                               unsigned short* __restrict__ x1b,
                                               float2* __restrict__ partials) {
  __shared__ unsigned int lds_c[384 * 9];   // raw centers, packed bf16x2, pad 9
  __shared__ unsigned int lds_a[384 * 9];   // conv outputs, packed bf16x2
  __shared__ float ls[4], lq[4];

  int tx = threadIdx.x;          // 0..31 (px-column triple)
  int ty = threadIdx.y;          // 0..7  (channel pair)
  int tid = ty * 32 + tx;
  int hb = blockIdx.x;           // 0..23
  int g  = blockIdx.y;           // 0..7
  int n  = blockIdx.z;
  int h0 = hb * 4;
  int w0 = tx * 3;

  const int c0 = g * 16 + 2 * ty;
  float wk[2][9];
  const float* wp = dw_w + c0 * 9;
#pragma unroll
  for (int j = 0; j < 9; ++j) {
    wk[0][j] = wp[j];
    wk[1][j] = wp[9 + j];
  }
  float bias[2] = {dw_b[c0], dw_b[c0 + 1]};

  const float* xp0 = x + ((size_t)(n * C_ + c0)) * HW_;
  const float* xp1 = xp0 + HW_;

  float s = 0.0f, q = 0.0f;

  float rr[3][2][5];
  loadrow5(rr[0], xp0, xp1, h0 - 1, w0);
  loadrow5(rr[1], xp0, xp1, h0,     w0);

#pragma unroll
  for (int r = 0; r < 4; ++r) {
    const int sA = r % 3;                // row h0+r-1
    const int sB = (r + 1) % 3;          // row h0+r
    const int sC = (r + 2) % 3;          // row h0+r+1
    loadrow5(rr[sC], xp0, xp1, h0 + r + 1, w0);

#pragma unroll
    for (int j = 0; j < 3; ++j) {
      float acc0 = bias[0], acc1 = bias[1];
#pragma unroll
      for (int dx = 0; dx < 3; ++dx) {
        acc0 = fmaf(rr[sA][0][j + dx], wk[0][0 + dx], acc0);
        acc1 = fmaf(rr[sA][1][j + dx], wk[1][0 + dx], acc1);
        acc0 = fmaf(rr[sB][0][j + dx], wk[0][3 + dx], acc0);
        acc1 = fmaf(rr[sB][1][j + dx], wk[1][3 + dx], acc1);
        acc0 = fmaf(rr[sC][0][j + dx], wk[0][6 + dx], acc0);
        acc1 = fmaf(rr[sC][1][j + dx], wk[1][6 + dx], acc1);
      }
      float cen0 = rr[sB][0][j + 1];
      float cen1 = rr[sB][1][j + 1];
      s += acc0 + acc1;
      q = fmaf(acc0, acc0, q);
      q = fmaf(acc1, acc1, q);
      int pxl = r * 96 + w0 + j;          // 0..383
      lds_a[pxl * 9 + ty] = pk_bf2(acc0, acc1);
      lds_c[pxl * 9 + ty] = pk_bf2(cen0, cen1);
    }
  }
  __syncthreads();

  // write-out: px-major, 32B per px per tile, fully coalesced per row
  for (int i = tid; i < 384; i += 256) {
    int row = i / 96;
    int col = i - row * 96;
    unsigned int wc[8], wa[8];
#pragma unroll
    for (int k = 0; k < 8; ++k) {
      wc[k] = lds_c[i * 9 + k];
      wa[k] = lds_a[i * 9 + k];
    }
    // padded group-planar raw x
    unsigned int* xg = (unsigned int*)xgb + (size_t)(n * G_ + g) * (PPLANE_ / 2)
                       + ((h0 + row + 2) * PW_ + (col + 2)) * 8;
    uint4 c01 = {wc[0], wc[1], wc[2], wc[3]};
    uint4 c23 = {wc[4], wc[5], wc[6], wc[7]};
    *(uint4*)xg = c01;
    *(uint4*)(xg + 4) = c23;
    // NHWC conv output
    int p = (h0 + row) * W_ + col;
    unsigned int* xb = (unsigned int*)x1b + ((size_t)n * HW_ + p) * 64 + g * 8;
    uint4 a01 = {wa[0], wa[1], wa[2], wa[3]};
    uint4 a23 = {wa[4], wa[5], wa[6], wa[7]};
    *(uint4*)xb = a01;
    *(uint4*)(xb + 4) = a23;
  }

  // block reduction of sum/sumsq
#pragma unroll
  for (int o = 32; o > 0; o >>= 1) {
    s += __shfl_down(s, o);
    q += __shfl_down(q, o);
  }
  int lane = tid & 63;
  int wv = tid >> 6;
  if (lane == 0) { ls[wv] = s; lq[wv] = q; }
  __syncthreads();
  if (tid == 0) {
    int bid = hb + 24 * g + BLKS_PER_N_ * n;
    partials[bid] = make_float2(ls[0] + ls[1] + ls[2] + ls[3],
                                lq[0] + lq[1] + lq[2] + lq[3]);
  }
}

// ---------------------------------------------------------------------------
// K1c (R14): blocks 0..111 permute+pad om_w -> A bf16 [224x128] + biasp;
// blocks 112..191 zero the xgb plane borders (784 px/plane * 64 planes,
// disjoint from k_front's interior writes -> safe in any launch order
// before k_sample). No dependency on k_front; launches first.
// ---------------------------------------------------------------------------
__global__ __launch_bounds__(256) void k_prep(const float* __restrict__ om_w,
                                              const float* __restrict__ om_b,
                                              unsigned short* __restrict__ A,
                                              float* __restrict__ biasp,
                                              unsigned short* __restrict__ xgb) {
  int b = blockIdx.x;
  int tid = threadIdx.x;
  if (b < 112) {
    int idx = b * 256 + tid;              // 0 .. 224*128-1
    int o = idx >> 7;
    int cix = idx & 127;
    int g = o / 28;
    int k = o - g * 28;
    float v = (k < 27) ? om_w[(g * 27 + k) * C_ + cix] : 0.0f;
    A[idx] = f2bf(v);
    if (cix == 0) biasp[o] = (k < 27) ? om_b[g * 27 + k] : 0.0f;
  } else {
    int gid = (b - 112) * 256 + tid;      // 0 .. 20479
    const int NBORD = 64 * 784;           // 50176 border px
    for (int id = gid; id < NBORD; id += 80 * 256) {
      int plane = id / 784;
      int r = id - plane * 784;
      int row, col;
      if (r < 400) {                      // rows 0,1,98,99 full width
        int qq = r / 100;
        row = (qq < 2) ? qq : qq + 96;
        col = r - qq * 100;
      } else {                            // rows 2..97, cols 0,1,98,99
        int r2 = r - 400;
        int qq = r2 >> 2;
        int c4 = r2 & 3;
        row = 2 + qq;
        col = (c4 < 2) ? c4 : c4 + 96;
      }
      uint4* dst = (uint4*)(xgb + (size_t)plane * PPLANE_ + (row * PW_ + col) * GC_);
      uint4 z = {0, 0, 0, 0};
      dst[0] = z;
      dst[1] = z;
    }
  }
}

// ---------------------------------------------------------------------------
// K4: MFMA GEMM with fused layernorm+GELU on B operand + inline per-sample
// stats reduction. 32-px tiles -> grid (288, 8); 4 waves as 2 px-halves x
// 2 ot-halves. R14: cvt_pk packing in staging and C-write.
// ---------------------------------------------------------------------------
__global__ __launch_bounds__(256) void k_gemm_mfma(const unsigned short* __restrict__ Bt,
                                                   const unsigned short* __restrict__ A,
                                                   const float* __restrict__ biasp,
                                                   const float2* __restrict__ partials,
                                                   const float* __restrict__ gn_w,
                                                   const float* __restrict__ gn_b,
                                                   unsigned int* __restrict__ om2) {
  __shared__ unsigned short Bl[32 * 136];
  __shared__ alignas(16) float s_bias[OMP_];
  __shared__ float ls[4], lq[4];
  int tid = threadIdx.x;
  int pb = blockIdx.x;
  int n = blockIdx.y;
  int p0 = pb * 32;

  // inline stats reduction (was k_stats): 192 partials for this n
  {
    float s = 0.0f, q = 0.0f;
    if (tid < BLKS_PER_N_) {
      float2 v = partials[n * BLKS_PER_N_ + tid];
      s = v.x;
      q = v.y;
    }
#pragma unroll
    for (int o = 32; o > 0; o >>= 1) {
      s += __shfl_down(s, o);
      q += __shfl_down(q, o);
    }
    int lane = tid & 63;
    int wv = tid >> 6;
    if (lane == 0) { ls[wv] = s; lq[wv] = q; }
  }
  if (tid < OMP_ / 4) {
    ((float4*)s_bias)[tid] = ((const float4*)biasp)[tid];
  }
  __syncthreads();

  float sum = ls[0] + ls[1] + ls[2] + ls[3];
  float ssq = lq[0] + lq[1] + lq[2] + lq[3];
  const float inv = 1.0f / (float)CHW_;
  float mean = sum * inv;
  float var = ssq * inv - mean * mean;
  float rstd = rsqrtf(var + EPS_);
  int cbase = (tid & 15) * 8;
  float a8[8], b8[8];
#pragma unroll
  for (int j = 0; j < 8; ++j) {
    float gw = gn_w[cbase + j];
    float gb = gn_b[cbase + j];
    a8[j] = rstd * gw;
    b8[j] = gb - mean * rstd * gw;
  }

  const unsigned short* src = Bt + ((size_t)n * HW_ + p0) * C_;
#pragma unroll
  for (int i = 0; i < 2; ++i) {
    int idx = i * 256 + tid;
    int row = idx >> 4;
    int col = idx & 15;                 // == tid & 15
    uint4 raw = *(const uint4*)(src + row * C_ + col * 8);
    unsigned int d[4] = {raw.x, raw.y, raw.z, raw.w};
    unsigned int od[4];
#pragma unroll
    for (int t = 0; t < 4; ++t) {
      float v0 = lo_bf(d[t]);
      float v1 = hi_bf(d[t]);
      float z0 = fmaf(v0, a8[2 * t], b8[2 * t]);
      float z1 = fmaf(v1, a8[2 * t + 1], b8[2 * t + 1]);
      od[t] = pk_bf2(fast_gelu(z0), fast_gelu(z1));
    }
    uint4 packed = {od[0], od[1], od[2], od[3]};
    *(uint4*)(&Bl[row * 136 + col * 8]) = packed;
  }
  __syncthreads();

  int wave = tid >> 6;
  int lane = tid & 63;
  int quad = lane >> 4;
  int l16 = lane & 15;
  int pixhalf = wave & 1;               // which 16-px half of the tile
  int othalf = wave >> 1;               // which half of the 14 o-tiles
  int prow = pixhalf * 16 + l16;

  bf16x8 bfrag[4];
#pragma unroll
  for (int kk = 0; kk < 4; ++kk)
    bfrag[kk] = *(const bf16x8*)(&Bl[prow * 136 + kk * 32 + quad * 8]);

  int p = p0 + prow;
  for (int oi = 0; oi < 7; ++oi) {
    int ot = othalf * 7 + oi;
    const unsigned short* Ap = A + (ot * 16 + l16) * C_ + quad * 8;
    bf16x8 afrag[4];
#pragma unroll
    for (int kk = 0; kk < 4; ++kk)
      afrag[kk] = *(const bf16x8*)(Ap + kk * 32);

    f32x4 acc = {0.f, 0.f, 0.f, 0.f};
#pragma unroll
    for (int kk = 0; kk < 4; ++kk)
      acc = __builtin_amdgcn_mfma_f32_16x16x32_bf16(afrag[kk], bfrag[kk], acc, 0, 0, 0);

    int o0 = ot * 16 + quad * 4;               // even
    float4 bv = *(const float4*)(&s_bias[o0]);
    unsigned int pk0 = pk_bf2(acc[0] + bv.x, acc[1] + bv.y);
    unsigned int pk1 = pk_bf2(acc[2] + bv.z, acc[3] + bv.w);
    unsigned int* Cp = om2 + ((size_t)n * OMROWS2_ + (o0 >> 1)) * HW_ + p;
    Cp[0] = pk0;
    Cp[HW_] = pk1;
  }
}

// ---------------------------------------------------------------------------
// K5 (R14): deformable bilinear sampling from PADDED group-planar xgb.
// Zero border (pad 2) makes out-of-bounds corners read 0.0 -> phase 1 loses
// all validity masks and x-redistribution (~35 of ~75 ops/job): just
// floor/lerp, 4 weight muls, 2 cvt_pk packs, clamped padded index (clamp to
// [-2,96] only guards |off|>=1 outliers -- clamped rows/cols are border
// zeros, still exact). Phase 2 unchanged: 4 lanes/px, 1 ds_read_b128 +
// 2 global dwordx4 + 8 v_perm + 8 v_dot2 per pt; __shfl_xor(2) folds x-cols.
// ---------------------------------------------------------------------------
__global__ __launch_bounds__(256) void k_sample(const unsigned short* __restrict__ xgb,
                                                const unsigned int* __restrict__ om2,
                                                float* __restrict__ out) {
  __shared__ int4 s_wa[9 * 64];   // {w_col0 pair, w_col1 pair, off_y0, off_y1}

  int tid = threadIdx.x;
  int ord = blockIdx.x;
  int n = ord & 7;
  int t2 = ord >> 3;
  int g = t2 & 7;
  int pb = t2 >> 3;
  int p0 = pb * 64;

  const unsigned int* omb = om2 + ((size_t)n * OMROWS2_ + g * 14) * HW_ + p0;
  for (int j = tid; j < 576; j += 256) {
    int pt = j >> 6;
    int px = j & 63;
    int p = p0 + px;
    int h = p / W_;
    int w = p - h * W_;
    unsigned int od = omb[pt * HW_ + px];
    float offx = lo_bf(od);
    float offy = hi_bf(od);
    unsigned int md = omb[(9 + (pt >> 1)) * HW_ + px];
    float m = (pt & 1) ? hi_bf(md) : lo_bf(md);
    float locy = (float)(h + pt / 3 - 1) + offy;
    float locx = (float)(w + pt % 3 - 1) + offx;
    float y0f = floorf(locy);
    float x0f = floorf(locx);
    float ly = locy - y0f;
    float lx = locx - x0f;
    int y0 = (int)y0f;
    int x0 = (int)x0f;
    y0 = min(max(y0, -2), 96);     // clamp into padded range; clamped rows are zero
    x0 = min(max(x0, -2), 96);
    float t0 = (1.0f - ly) * m;
    float t1 = ly * m;
    float u0 = 1.0f - lx;
    int4 wa;
    wa.x = (int)pk_bf2(t0 * u0, t1 * u0);   // x-col0: (y0 w, y1 w)
    wa.y = (int)pk_bf2(t0 * lx, t1 * lx);   // x-col1: (y0 w, y1 w)
    wa.z = ((y0 + 2) * PW_ + (x0 + 2)) * GC_;   // padded row y0, 2-px segment
    wa.w = wa.z + PW_ * GC_;                    // padded row y1
    s_wa[j] = wa;
  }
  __syncthreads();

  int px_l = tid >> 2;             // 0..63
  int sub = tid & 3;               // bit1 = x-col, bit0 = channel-chunk
  int rowhalf = sub >> 1;
  int chunk = sub & 1;
  int p = p0 + px_l;
  const unsigned short* xbb = xgb + (size_t)(n * G_ + g) * PPLANE_;

  float acc[8] = {0, 0, 0, 0, 0, 0, 0, 0};
#pragma unroll
  for (int pt = 0; pt < 9; ++pt) {
    int4 wa = s_wa[pt * 64 + px_l];
    unsigned int aw = (unsigned int)(rowhalf ? wa.y : wa.x);  // (w_y0, w_y1) bf16x2
    uint4 r0 = *(const uint4*)(xbb + wa.z + sub * 8);         // y0 row, 2-px seg
    uint4 r1 = *(const uint4*)(xbb + wa.w + sub * 8);         // y1 row, 2-px seg
    unsigned int d0[4] = {r0.x, r0.y, r0.z, r0.w};
    unsigned int d1[4] = {r1.x, r1.y, r1.z, r1.w};
#if HAVE_DOT2_
    bf16x2 a2 = u2bf2(aw);
#pragma unroll
    for (int t = 0; t < 4; ++t) {
      unsigned int blo = __builtin_amdgcn_perm(d1[t], d0[t], 0x05040100u); // (v_y0.lo, v_y1.lo)
      unsigned int bhi = __builtin_amdgcn_perm(d1[t], d0[t], 0x07060302u); // (v_y0.hi, v_y1.hi)
      acc[2 * t]     = __builtin_amdgcn_fdot2_f32_bf16(a2, u2bf2(blo), acc[2 * t], false);
      acc[2 * t + 1] = __builtin_amdgcn_fdot2_f32_bf16(a2, u2bf2(bhi), acc[2 * t + 1], false);
    }
#else
    float w0 = lo_bf(aw);
    float w1 = hi_bf(aw);
#pragma unroll
    for (int t = 0; t < 4; ++t) {
      acc[2 * t]     = fmaf(w0, lo_bf(d0[t]), acc[2 * t]);
      acc[2 * t + 1] = fmaf(w0, hi_bf(d0[t]), acc[2 * t + 1]);
      acc[2 * t]     = fmaf(w1, lo_bf(d1[t]), acc[2 * t]);
      acc[2 * t + 1] = fmaf(w1, hi_bf(d1[t]), acc[2 * t + 1]);
    }
#endif
  }

  // fold the two x-cols (lanes sub and sub^2 hold the same 8 channels)
#pragma unroll
  for (int i = 0; i < 8; ++i) acc[i] += __shfl_xor(acc[i], 2);

  int ch = chunk * 8 + rowhalf * 4;
  float* op = out + ((size_t)(n * C_ + g * GC_ + ch)) * HW_ + p;
#pragma unroll
  for (int r = 0; r < 4; ++r) op[r * HW_] = acc[rowhalf * 4 + r];
}

// ---------------------------------------------------------------------------
extern "C" void kernel_launch(void* const* d_in, const int* in_sizes, int n_in,
                              void* d_out, int out_size, void* d_ws, size_t ws_size,
                              hipStream_t stream) {
  const float* x    = (const float*)d_in[0];
  const float* dw_w = (const float*)d_in[1];
  const float* dw_b = (const float*)d_in[2];
  const float* gn_w = (const float*)d_in[3];
  const float* gn_b = (const float*)d_in[4];
  const float* om_w = (const float*)d_in[5];
  const float* om_b = (const float*)d_in[6];
  float* out = (float*)d_out;

  // workspace layout (~76 MB)
  unsigned short* xgb = (unsigned short*)d_ws;                       // 64 * 160000 us (padded planes)
  unsigned short* x1b = xgb + (size_t)64 * PPLANE_;                  // 9437184 us
  unsigned int* om2 = (unsigned int*)(x1b + (size_t)N_ * CHW_);      // 8*112*9216 u32
  float* stats = (float*)(om2 + (size_t)N_ * OMROWS2_ * HW_);        // 16 f (unused)
  float2* partials = (float2*)(stats + 16);                          // 1536 float2
  unsigned short* Abf = (unsigned short*)(partials + N_ * BLKS_PER_N_);
  float* biasp = (float*)(Abf + OMP_ * C_);                          // 224 f

  k_prep<<<192, 256, 0, stream>>>(om_w, om_b, Abf, biasp, xgb);
  k_front<<<dim3(24, G_, N_), dim3(32, 8), 0, stream>>>(
      x, dw_w, dw_b, xgb, x1b, partials);
  k_gemm_mfma<<<dim3(HW_ / 32, N_), 256, 0, stream>>>(
      x1b, Abf, biasp, partials, gn_w, gn_b, om2);
  k_sample<<<9216, 256, 0, stream>>>(xgb, om2, out);
}

// Round 7
// 180.439 us; speedup vs baseline: 1.0751x; 1.0071x over previous
//
#include <hip/hip_runtime.h>
#include <hip/hip_bf16.h>

#define N_   8
#define C_   128
#define H_   96
#define W_   96
#define G_   8
#define GC_  16
#define HW_  (H_ * W_)       // 9216
#define CHW_ (C_ * HW_)      // 1179648
#define OM_  216
#define OMP_ 224             // padded: 8 groups x 28 rows (27 live + 1 pad)
#define OMROWS2_ 112         // packed dword rows per sample (224/2)
#define EPS_ 1e-5f
#define BLKS_PER_N_ 192      // k_front blocks per sample (24 h-tiles * 8 groups)
#define PW_  100             // padded plane width (96 + 2*2)
#define PPLANE_ (PW_ * PW_ * GC_)   // shorts per padded (n,g) plane = 160000

typedef short bf16x8 __attribute__((ext_vector_type(8)));
typedef float f32x4 __attribute__((ext_vector_type(4)));

#if __has_builtin(__builtin_amdgcn_fdot2_f32_bf16)
#define HAVE_DOT2_ 1
typedef __bf16 bf16x2 __attribute__((ext_vector_type(2)));
static __device__ __forceinline__ bf16x2 u2bf2(unsigned int u) {
  union { unsigned int i; bf16x2 v; } c;
  c.i = u;
  return c.v;
}
#else
#define HAVE_DOT2_ 0
#endif

static __device__ __forceinline__ unsigned short f2bf(float f) {
  unsigned int u = __float_as_uint(f);
  unsigned int r = (u + 0x7fffu + ((u >> 16) & 1u)) >> 16;
  return (unsigned short)r;
}
// Packed f32x2 -> bf16x2 via v_cvt_pk_bf16_f32 (1 instr, RTNE -- bit-identical
// to f2bf's manual rounding).
static __device__ __forceinline__ unsigned int pk_bf2(float lo, float hi) {
  __hip_bfloat162 h = __float22bfloat162_rn(make_float2(lo, hi));
  union { __hip_bfloat162 h; unsigned int u; } c;
  c.h = h;
  return c.u;
}
static __device__ __forceinline__ float lo_bf(unsigned int u) {
  return __uint_as_float(u << 16);
}
static __device__ __forceinline__ float hi_bf(unsigned int u) {
  return __uint_as_float(u & 0xffff0000u);
}

// Branch-free exact-GELU via Abramowitz-Stegun 7.1.26 erf (|err| <= 1.5e-7,
// far below the bf16 quantization already applied to x1).
static __device__ __forceinline__ float fast_gelu(float z) {
  float s = z * 0.70710678118654752f;
  float as = fabsf(s);
  float t = __builtin_amdgcn_rcpf(fmaf(0.3275911f, as, 1.0f));
  float e = __expf(-as * as);
  float inner = fmaf(fmaf(fmaf(fmaf(1.061405429f, t, -1.453152027f), t,
                               1.421413741f), t, -0.284496736f), t, 0.254829592f);
  float y = fmaf(-inner * t, e, 1.0f);          // erf(|s|)
  float erf_s = copysignf(y, s);
  float hz = 0.5f * z;
  return fmaf(hz, erf_s, hz);
}

// Load one input row (5 cols: w0-1 .. w0+3) for a channel pair, zero-masked.
static __device__ __forceinline__ void loadrow5(float dst[2][5],
                                                const float* __restrict__ xp0,
                                                const float* __restrict__ xp1,
                                                int hh, int w0) {
  bool vy = (hh >= 0) & (hh < H_);
#pragma unroll
  for (int j = 0; j < 5; ++j) {
    int ww = w0 - 1 + j;
    bool v = vy & (ww >= 0) & (ww < W_);
    dst[0][j] = v ? xp0[hh * W_ + ww] : 0.0f;
    dst[1][j] = v ? xp1[hh * W_ + ww] : 0.0f;
  }
}

// ---------------------------------------------------------------------------
// K1 (fused): tile = 4 h x 96 w x 16 ch, grid (24, 8, 8) = 1536 blocks; LDS
// 27.6 KB -> 5 blocks/CU. Thread = channel-pair x 3 px-cols, rolling 3x5
// register window; pad-9 dword LDS transpose; cvt_pk bf16 packing.
// xgb written as zero-padded 100x100 plane (border pre-zeroed by k_prep).
// ---------------------------------------------------------------------------
__global__ __launch_bounds__(256) void k_front(const float* __restrict__ x,
                                               const float* __restrict__ dw_w,
                                               const float* __restrict__ dw_b,
                                               unsigned short* __restrict__ xgb,
                                               unsigned short* __restrict__ x1b,
                                               float2* __restrict__ partials) {
  __shared__ unsigned int lds_c[384 * 9];   // raw centers, packed bf16x2, pad 9
  __shared__ unsigned int lds_a[384 * 9];   // conv outputs, packed bf16x2
  __shared__ float ls[4], lq[4];

  int tx = threadIdx.x;          // 0..31 (px-column triple)
  int ty = threadIdx.y;          // 0..7  (channel pair)
  int tid = ty * 32 + tx;
  int hb = blockIdx.x;           // 0..23
  int g  = blockIdx.y;           // 0..7
  int n  = blockIdx.z;
  int h0 = hb * 4;
  int w0 = tx * 3;

  const int c0 = g * 16 + 2 * ty;
  float wk[2][9];
  const float* wp = dw_w + c0 * 9;
#pragma unroll
  for (int j = 0; j < 9; ++j) {
    wk[0][j] = wp[j];
    wk[1][j] = wp[9 + j];
  }
  float bias[2] = {dw_b[c0], dw_b[c0 + 1]};

  const float* xp0 = x + ((size_t)(n * C_ + c0)) * HW_;
  const float* xp1 = xp0 + HW_;

  float s = 0.0f, q = 0.0f;

  float rr[3][2][5];
  loadrow5(rr[0], xp0, xp1, h0 - 1, w0);
  loadrow5(rr[1], xp0, xp1, h0,     w0);

#pragma unroll
  for (int r = 0; r < 4; ++r) {
    const int sA = r % 3;                // row h0+r-1
    const int sB = (r + 1) % 3;          // row h0+r
    const int sC = (r + 2) % 3;          // row h0+r+1
    loadrow5(rr[sC], xp0, xp1, h0 + r + 1, w0);

#pragma unroll
    for (int j = 0; j < 3; ++j) {
      float acc0 = bias[0], acc1 = bias[1];
#pragma unroll
      for (int dx = 0; dx < 3; ++dx) {
        acc0 = fmaf(rr[sA][0][j + dx], wk[0][0 + dx], acc0);
        acc1 = fmaf(rr[sA][1][j + dx], wk[1][0 + dx], acc1);
        acc0 = fmaf(rr[sB][0][j + dx], wk[0][3 + dx], acc0);
        acc1 = fmaf(rr[sB][1][j + dx], wk[1][3 + dx], acc1);
        acc0 = fmaf(rr[sC][0][j + dx], wk[0][6 + dx], acc0);
        acc1 = fmaf(rr[sC][1][j + dx], wk[1][6 + dx], acc1);
      }
      float cen0 = rr[sB][0][j + 1];
      float cen1 = rr[sB][1][j + 1];
      s += acc0 + acc1;
      q = fmaf(acc0, acc0, q);
      q = fmaf(acc1, acc1, q);
      int pxl = r * 96 + w0 + j;          // 0..383
      lds_a[pxl * 9 + ty] = pk_bf2(acc0, acc1);
      lds_c[pxl * 9 + ty] = pk_bf2(cen0, cen1);
    }
  }
  __syncthreads();

  // write-out: px-major, 32B per px per tile, fully coalesced per row
  for (int i = tid; i < 384; i += 256) {
    int row = i / 96;
    int col = i - row * 96;
    unsigned int wc[8], wa[8];
#pragma unroll
    for (int k = 0; k < 8; ++k) {
      wc[k] = lds_c[i * 9 + k];
      wa[k] = lds_a[i * 9 + k];
    }
    // padded group-planar raw x
    unsigned int* xg = (unsigned int*)xgb + (size_t)(n * G_ + g) * (PPLANE_ / 2)
                       + ((h0 + row + 2) * PW_ + (col + 2)) * 8;
    uint4 c01 = {wc[0], wc[1], wc[2], wc[3]};
    uint4 c23 = {wc[4], wc[5], wc[6], wc[7]};
    *(uint4*)xg = c01;
    *(uint4*)(xg + 4) = c23;
    // NHWC conv output
    int p = (h0 + row) * W_ + col;
    unsigned int* xb = (unsigned int*)x1b + ((size_t)n * HW_ + p) * 64 + g * 8;
    uint4 a01 = {wa[0], wa[1], wa[2], wa[3]};
    uint4 a23 = {wa[4], wa[5], wa[6], wa[7]};
    *(uint4*)xb = a01;
    *(uint4*)(xb + 4) = a23;
  }

  // block reduction of sum/sumsq
#pragma unroll
  for (int o = 32; o > 0; o >>= 1) {
    s += __shfl_down(s, o);
    q += __shfl_down(q, o);
  }
  int lane = tid & 63;
  int wv = tid >> 6;
  if (lane == 0) { ls[wv] = s; lq[wv] = q; }
  __syncthreads();
  if (tid == 0) {
    int bid = hb + 24 * g + BLKS_PER_N_ * n;
    partials[bid] = make_float2(ls[0] + ls[1] + ls[2] + ls[3],
                                lq[0] + lq[1] + lq[2] + lq[3]);
  }
}

// ---------------------------------------------------------------------------
// K1c: blocks 0..111 permute+pad om_w -> A bf16 [224x128] + biasp;
// blocks 112..191 zero the xgb plane borders. No dependency on k_front;
// launches first.
// ---------------------------------------------------------------------------
__global__ __launch_bounds__(256) void k_prep(const float* __restrict__ om_w,
                                              const float* __restrict__ om_b,
                                              unsigned short* __restrict__ A,
                                              float* __restrict__ biasp,
                                              unsigned short* __restrict__ xgb) {
  int b = blockIdx.x;
  int tid = threadIdx.x;
  if (b < 112) {
    int idx = b * 256 + tid;              // 0 .. 224*128-1
    int o = idx >> 7;
    int cix = idx & 127;
    int g = o / 28;
    int k = o - g * 28;
    float v = (k < 27) ? om_w[(g * 27 + k) * C_ + cix] : 0.0f;
    A[idx] = f2bf(v);
    if (cix == 0) biasp[o] = (k < 27) ? om_b[g * 27 + k] : 0.0f;
  } else {
    int gid = (b - 112) * 256 + tid;      // 0 .. 20479
    const int NBORD = 64 * 784;           // 50176 border px
    for (int id = gid; id < NBORD; id += 80 * 256) {
      int plane = id / 784;
      int r = id - plane * 784;
      int row, col;
      if (r < 400) {                      // rows 0,1,98,99 full width
        int qq = r / 100;
        row = (qq < 2) ? qq : qq + 96;
        col = r - qq * 100;
      } else {                            // rows 2..97, cols 0,1,98,99
        int r2 = r - 400;
        int qq = r2 >> 2;
        int c4 = r2 & 3;
        row = 2 + qq;
        col = (c4 < 2) ? c4 : c4 + 96;
      }
      uint4* dst = (uint4*)(xgb + (size_t)plane * PPLANE_ + (row * PW_ + col) * GC_);
      uint4 z = {0, 0, 0, 0};
      dst[0] = z;
      dst[1] = z;
    }
  }
}

// A-fragment prefetch helper (4 x 16B loads for one o-tile).
static __device__ __forceinline__ void pref_af(bf16x8 (&af)[4],
                                               const unsigned short* __restrict__ A,
                                               int ot, int l16, int quad) {
  const unsigned short* Ap = A + (ot * 16 + l16) * C_ + quad * 8;
#pragma unroll
  for (int kk = 0; kk < 4; ++kk) af[kk] = *(const bf16x8*)(Ap + kk * 32);
}

// ---------------------------------------------------------------------------
// K4 (R15): MFMA GEMM, software-pipelined. Previous form was a device-wide
// phase-burst (whole 9216-wave grid co-resident, each phase's loads issued
// on demand -> full L2 latency per phase; MfmaUtil 3.5%, VALUBusy 18%,
// Occ 34%). Now: (a) staging x1b loads + gn_w/gn_b + bias issued BEFORE the
// stats reduction (latency hides under it); (b) per-ot A-fragment loads
// double-buffered with a fully static 7-step prefetch chain (load ot+1
// during MFMA of ot). VGPR ~44 -> ~130 (3 waves/SIMD) -- trades idle wave
// slots for in-wave ILP.
// ---------------------------------------------------------------------------
__global__ __launch_bounds__(256) void k_gemm_mfma(const unsigned short* __restrict__ Bt,
                                                   const unsigned short* __restrict__ A,
                                                   const float* __restrict__ biasp,
                                                   const float2* __restrict__ partials,
                                                   const float* __restrict__ gn_w,
                                                   const float* __restrict__ gn_b,
                                                   unsigned int* __restrict__ om2) {
  __shared__ unsigned short Bl[32 * 136];
  __shared__ alignas(16) float s_bias[OMP_];
  __shared__ float ls[4], lq[4];
  int tid = threadIdx.x;
  int pb = blockIdx.x;
  int n = blockIdx.y;
  int p0 = pb * 32;

  // ---- issue all long-latency loads first ----
  const unsigned short* src = Bt + ((size_t)n * HW_ + p0) * C_;
  int col = tid & 15;
  int row0 = tid >> 4;                  // 0..15
  uint4 raw0 = *(const uint4*)(src + row0 * C_ + col * 8);
  uint4 raw1 = *(const uint4*)(src + (16 + row0) * C_ + col * 8);
  int cbase = col * 8;
  float gw8[8], gb8[8];
#pragma unroll
  for (int j = 0; j < 8; ++j) {
    gw8[j] = gn_w[cbase + j];
    gb8[j] = gn_b[cbase + j];
  }
  if (tid < OMP_ / 4) {
    ((float4*)s_bias)[tid] = ((const float4*)biasp)[tid];
  }

  // ---- stats reduction (its loads overlap the ones above) ----
  {
    float s = 0.0f, q = 0.0f;
    if (tid < BLKS_PER_N_) {
      float2 v = partials[n * BLKS_PER_N_ + tid];
      s = v.x;
      q = v.y;
    }
#pragma unroll
    for (int o = 32; o > 0; o >>= 1) {
      s += __shfl_down(s, o);
      q += __shfl_down(q, o);
    }
    int lane = tid & 63;
    int wv = tid >> 6;
    if (lane == 0) { ls[wv] = s; lq[wv] = q; }
  }
  __syncthreads();

  float sum = ls[0] + ls[1] + ls[2] + ls[3];
  float ssq = lq[0] + lq[1] + lq[2] + lq[3];
  const float inv = 1.0f / (float)CHW_;
  float mean = sum * inv;
  float var = ssq * inv - mean * mean;
  float rstd = rsqrtf(var + EPS_);
  float a8[8], b8[8];
#pragma unroll
  for (int j = 0; j < 8; ++j) {
    a8[j] = rstd * gw8[j];
    b8[j] = gb8[j] - mean * rstd * gw8[j];
  }

  // ---- LN+GELU on the pre-staged raws, write to LDS ----
  {
    uint4 raws[2] = {raw0, raw1};
#pragma unroll
    for (int i = 0; i < 2; ++i) {
      int row = row0 + i * 16;
      unsigned int d[4] = {raws[i].x, raws[i].y, raws[i].z, raws[i].w};
      unsigned int od[4];
#pragma unroll
      for (int t = 0; t < 4; ++t) {
        float v0 = lo_bf(d[t]);
        float v1 = hi_bf(d[t]);
        float z0 = fmaf(v0, a8[2 * t], b8[2 * t]);
        float z1 = fmaf(v1, a8[2 * t + 1], b8[2 * t + 1]);
        od[t] = pk_bf2(fast_gelu(z0), fast_gelu(z1));
      }
      uint4 packed = {od[0], od[1], od[2], od[3]};
      *(uint4*)(&Bl[row * 136 + col * 8]) = packed;
    }
  }
  __syncthreads();

  int wave = tid >> 6;
  int lane = tid & 63;
  int quad = lane >> 4;
  int l16 = lane & 15;
  int pixhalf = wave & 1;               // which 16-px half of the tile
  int othalf = wave >> 1;               // which half of the 14 o-tiles
  int prow = pixhalf * 16 + l16;

  bf16x8 bfrag[4];
#pragma unroll
  for (int kk = 0; kk < 4; ++kk)
    bfrag[kk] = *(const bf16x8*)(&Bl[prow * 136 + kk * 32 + quad * 8]);

  int p = p0 + prow;
  int base = othalf * 7;

  // compute+store for one o-tile from a given fragment buffer
#define COMP_(AF, OT)                                                          \
  {                                                                            \
    f32x4 acc = {0.f, 0.f, 0.f, 0.f};                                          \
    _Pragma("unroll")                                                          \
    for (int kk = 0; kk < 4; ++kk)                                             \
      acc = __builtin_amdgcn_mfma_f32_16x16x32_bf16(AF[kk], bfrag[kk], acc,    \
                                                    0, 0, 0);                  \
    int o0 = (OT) * 16 + quad * 4;                                             \
    float4 bv = *(const float4*)(&s_bias[o0]);                                 \
    unsigned int pk0 = pk_bf2(acc[0] + bv.x, acc[1] + bv.y);                   \
    unsigned int pk1 = pk_bf2(acc[2] + bv.z, acc[3] + bv.w);                   \
    unsigned int* Cp = om2 + ((size_t)n * OMROWS2_ + (o0 >> 1)) * HW_ + p;     \
    Cp[0] = pk0;                                                               \
    Cp[HW_] = pk1;                                                             \
  }

  bf16x8 af0[4], af1[4];
  pref_af(af0, A, base + 0, l16, quad);
  pref_af(af1, A, base + 1, l16, quad);
  COMP_(af0, base + 0);
  pref_af(af0, A, base + 2, l16, quad);
  COMP_(af1, base + 1);
  pref_af(af1, A, base + 3, l16, quad);
  COMP_(af0, base + 2);
  pref_af(af0, A, base + 4, l16, quad);
  COMP_(af1, base + 3);
  pref_af(af1, A, base + 5, l16, quad);
  COMP_(af0, base + 4);
  pref_af(af0, A, base + 6, l16, quad);
  COMP_(af1, base + 5);
  COMP_(af0, base + 6);
#undef COMP_
}

// ---------------------------------------------------------------------------
// K5: deformable bilinear sampling from PADDED group-planar xgb. Zero border
// (pad 2) removes all validity masks from phase 1. Phase 2: 4 lanes/px,
// 1 ds_read_b128 + 2 global dwordx4 + 8 v_perm + 8 v_dot2 per pt;
// __shfl_xor(2) folds x-cols.
// ---------------------------------------------------------------------------
__global__ __launch_bounds__(256) void k_sample(const unsigned short* __restrict__ xgb,
                                                const unsigned int* __restrict__ om2,
                                                float* __restrict__ out) {
  __shared__ int4 s_wa[9 * 64];   // {w_col0 pair, w_col1 pair, off_y0, off_y1}

  int tid = threadIdx.x;
  int ord = blockIdx.x;
  int n = ord & 7;
  int t2 = ord >> 3;
  int g = t2 & 7;
  int pb = t2 >> 3;
  int p0 = pb * 64;

  const unsigned int* omb = om2 + ((size_t)n * OMROWS2_ + g * 14) * HW_ + p0;
  for (int j = tid; j < 576; j += 256) {
    int pt = j >> 6;
    int px = j & 63;
    int p = p0 + px;
    int h = p / W_;
    int w = p - h * W_;
    unsigned int od = omb[pt * HW_ + px];
    float offx = lo_bf(od);
    float offy = hi_bf(od);
    unsigned int md = omb[(9 + (pt >> 1)) * HW_ + px];
    float m = (pt & 1) ? hi_bf(md) : lo_bf(md);
    float locy = (float)(h + pt / 3 - 1) + offy;
    float locx = (float)(w + pt % 3 - 1) + offx;
    float y0f = floorf(locy);
    float x0f = floorf(locx);
    float ly = locy - y0f;
    float lx = locx - x0f;
    int y0 = (int)y0f;
    int x0 = (int)x0f;
    y0 = min(max(y0, -2), 96);     // clamp into padded range; clamped rows are zero
    x0 = min(max(x0, -2), 96);
    float t0 = (1.0f - ly) * m;
    float t1 = ly * m;
    float u0 = 1.0f - lx;
    int4 wa;
    wa.x = (int)pk_bf2(t0 * u0, t1 * u0);   // x-col0: (y0 w, y1 w)
    wa.y = (int)pk_bf2(t0 * lx, t1 * lx);   // x-col1: (y0 w, y1 w)
    wa.z = ((y0 + 2) * PW_ + (x0 + 2)) * GC_;   // padded row y0, 2-px segment
    wa.w = wa.z + PW_ * GC_;                    // padded row y1
    s_wa[j] = wa;
  }
  __syncthreads();

  int px_l = tid >> 2;             // 0..63
  int sub = tid & 3;               // bit1 = x-col, bit0 = channel-chunk
  int rowhalf = sub >> 1;
  int chunk = sub & 1;
  int p = p0 + px_l;
  const unsigned short* xbb = xgb + (size_t)(n * G_ + g) * PPLANE_;

  float acc[8] = {0, 0, 0, 0, 0, 0, 0, 0};
#pragma unroll
  for (int pt = 0; pt < 9; ++pt) {
    int4 wa = s_wa[pt * 64 + px_l];
    unsigned int aw = (unsigned int)(rowhalf ? wa.y : wa.x);  // (w_y0, w_y1) bf16x2
    uint4 r0 = *(const uint4*)(xbb + wa.z + sub * 8);         // y0 row, 2-px seg
    uint4 r1 = *(const uint4*)(xbb + wa.w + sub * 8);         // y1 row, 2-px seg
    unsigned int d0[4] = {r0.x, r0.y, r0.z, r0.w};
    unsigned int d1[4] = {r1.x, r1.y, r1.z, r1.w};
#if HAVE_DOT2_
    bf16x2 a2 = u2bf2(aw);
#pragma unroll
    for (int t = 0; t < 4; ++t) {
      unsigned int blo = __builtin_amdgcn_perm(d1[t], d0[t], 0x05040100u); // (v_y0.lo, v_y1.lo)
      unsigned int bhi = __builtin_amdgcn_perm(d1[t], d0[t], 0x07060302u); // (v_y0.hi, v_y1.hi)
      acc[2 * t]     = __builtin_amdgcn_fdot2_f32_bf16(a2, u2bf2(blo), acc[2 * t], false);
      acc[2 * t + 1] = __builtin_amdgcn_fdot2_f32_bf16(a2, u2bf2(bhi), acc[2 * t + 1], false);
    }
#else
    float w0 = lo_bf(aw);
    float w1 = hi_bf(aw);
#pragma unroll
    for (int t = 0; t < 4; ++t) {
      acc[2 * t]     = fmaf(w0, lo_bf(d0[t]), acc[2 * t]);
      acc[2 * t + 1] = fmaf(w0, hi_bf(d0[t]), acc[2 * t + 1]);
      acc[2 * t]     = fmaf(w1, lo_bf(d1[t]), acc[2 * t]);
      acc[2 * t + 1] = fmaf(w1, hi_bf(d1[t]), acc[2 * t + 1]);
    }
#endif
  }

  // fold the two x-cols (lanes sub and sub^2 hold the same 8 channels)
#pragma unroll
  for (int i = 0; i < 8; ++i) acc[i] += __shfl_xor(acc[i], 2);

  int ch = chunk * 8 + rowhalf * 4;
  float* op = out + ((size_t)(n * C_ + g * GC_ + ch)) * HW_ + p;
#pragma unroll
  for (int r = 0; r < 4; ++r) op[r * HW_] = acc[rowhalf * 4 + r];
}

// ---------------------------------------------------------------------------
extern "C" void kernel_launch(void* const* d_in, const int* in_sizes, int n_in,
                              void* d_out, int out_size, void* d_ws, size_t ws_size,
                              hipStream_t stream) {
  const float* x    = (const float*)d_in[0];
  const float* dw_w = (const float*)d_in[1];
  const float* dw_b = (const float*)d_in[2];
  const float* gn_w = (const float*)d_in[3];
  const float* gn_b = (const float*)d_in[4];
  const float* om_w = (const float*)d_in[5];
  const float* om_b = (const float*)d_in[6];
  float* out = (float*)d_out;

  // workspace layout (~76 MB)
  unsigned short* xgb = (unsigned short*)d_ws;                       // 64 * 160000 us (padded planes)
  unsigned short* x1b = xgb + (size_t)64 * PPLANE_;                  // 9437184 us
  unsigned int* om2 = (unsigned int*)(x1b + (size_t)N_ * CHW_);      // 8*112*9216 u32
  float* stats = (float*)(om2 + (size_t)N_ * OMROWS2_ * HW_);        // 16 f (unused)
  float2* partials = (float2*)(stats + 16);                          // 1536 float2
  unsigned short* Abf = (unsigned short*)(partials + N_ * BLKS_PER_N_);
  float* biasp = (float*)(Abf + OMP_ * C_);                          // 224 f

  k_prep<<<192, 256, 0, stream>>>(om_w, om_b, Abf, biasp, xgb);
  k_front<<<dim3(24, G_, N_), dim3(32, 8), 0, stream>>>(
      x, dw_w, dw_b, xgb, x1b, partials);
  k_gemm_mfma<<<dim3(HW_ / 32, N_), 256, 0, stream>>>(
      x1b, Abf, biasp, partials, gn_w, gn_b, om2);
  k_sample<<<9216, 256, 0, stream>>>(xgb, om2, out);
}